// Round 4
// baseline (98.221 us; speedup 1.0000x reference)
//
#include <hip/hip_runtime.h>

// Problem constants: B=8192, NJ=14, COL=14, sigma=1, radius=4.
#define NJ    14
#define TILE  196          // 14*14
#define BLK   256
#define JPB   64           // joints per block (one per lane; 4 waves split the tile)

// exp(-0.5*d*d) with the 9-tap cutoff (|d|<=4), via v_exp_f32.
__device__ __forceinline__ float gtap(int d) {
  const int d2 = d * d;
  const float e = exp2f(-0.72134752044448169f * (float)d2);  // 0.5*log2(e)
  return (d2 <= 16) ? e : 0.0f;
}

// 1-D blurred-impulse response at position p for peak pk, with scipy
// 'reflect' padding folded in. Unnormalized (kernel-sum cancels in g/max).
__device__ __forceinline__ float uresp(int p, int pk) {
  float s = gtap(p - pk);
  if (p <= 3)  s += gtap(p + pk + 1);   // low reflection  (q<0 -> -1-q)
  if (p >= 10) s += gtap(27 - p - pk);  // high reflection (q>13 -> 27-q)
  return s;
}

__device__ __forceinline__ float wave_sum(float x) {
#pragma unroll
  for (int off = 32; off >= 1; off >>= 1) x += __shfl_xor(x, off);
  return x;
}

// Wave K processes float4 indices f = 4i + K of its lane's tile.
// All tile indices are compile-time -> uy/ux stay in registers.
template<int K>
__device__ __forceinline__ void accum_part(const float4* __restrict__ hp,
    const float (&uy)[14], const float (&ux)[14],
    float& bm, int& bi, float& sh2, float& cross, float& q0)
{
  const int NI = (K == 0) ? 13 : 12;   // 49 float4 = 13+12+12+12
#pragma unroll
  for (int i = 0; i < NI; ++i) {
    const int f = 4 * i + K;
    const float4 q = hp[f];
    const float qa[4] = {q.x, q.y, q.z, q.w};
#pragma unroll
    for (int c = 0; c < 4; ++c) {
      const int idx = 4 * f + c;
      const int y = idx / 14;
      const int x = idx - 14 * y;            // compile-time
      const float hv = qa[c];
      if (hv > bm) { bm = hv; bi = idx; }    // first-index within part
      sh2 = fmaf(hv, hv, sh2);
      if (y == 0) q0 = fmaf(hv, hv, q0);     // row-0 energy (invis fixup)
      cross = fmaf(hv, uy[y] * ux[x], cross);
    }
  }
}

__global__ __launch_bounds__(BLK, 4) void joint_kernel(
    const float* __restrict__ o, const float* __restrict__ h,
    const float* __restrict__ t, const float* __restrict__ v,
    float* __restrict__ part, int* __restrict__ ticket,
    float* __restrict__ out, int njoint, int nblocks)
{
  __shared__ float sm_bm[4][JPB];
  __shared__ int   sm_bi[4][JPB];
  __shared__ float sm_s2[4][JPB];
  __shared__ float sm_cr[4][JPB];
  __shared__ float sm_q0[4][JPB];
  __shared__ int   s_last;

  const int lane = threadIdx.x & 63;
  const int wid  = threadIdx.x >> 6;
  const int jg   = blockIdx.x * JPB + lane;
  const bool valid = jg < njoint;

  float uy[14], ux[14];
  float bm = -3.0e38f; int bi = 0;
  float sh2 = 0.0f, cross = 0.0f, q0 = 0.0f;
  float2 tv = make_float2(0.0f, 0.0f);
  int xi = 0, yi = 0;

  if (valid) {
    tv = ((const float2*)t)[jg];
    xi = min(max((int)(tv.x * 14.0f), 0), 13);
    yi = min(max((int)(tv.y * 14.0f), 0), 13);
#pragma unroll
    for (int p = 0; p < 14; ++p) { uy[p] = uresp(p, yi); ux[p] = uresp(p, xi); }

    const float4* hp = (const float4*)(h + (size_t)jg * TILE);
    switch (wid) {   // wave-uniform branch: no lane divergence
      case 0: accum_part<0>(hp, uy, ux, bm, bi, sh2, cross, q0); break;
      case 1: accum_part<1>(hp, uy, ux, bm, bi, sh2, cross, q0); break;
      case 2: accum_part<2>(hp, uy, ux, bm, bi, sh2, cross, q0); break;
      default: accum_part<3>(hp, uy, ux, bm, bi, sh2, cross, q0); break;
    }
  }

  sm_bm[wid][lane] = bm;  sm_bi[wid][lane] = bi;
  sm_s2[wid][lane] = sh2; sm_cr[wid][lane] = cross; sm_q0[wid][lane] = q0;
  __syncthreads();

  if (wid == 0) {
    // ---- combine the 4 parts for this lane's joint ----
    float Bm = sm_bm[0][lane]; int Bi = sm_bi[0][lane];
    float S2 = sm_s2[0][lane], Cr = sm_cr[0][lane], Q0 = sm_q0[0][lane];
#pragma unroll
    for (int w = 1; w < 4; ++w) {
      const float m = sm_bm[w][lane]; const int i = sm_bi[w][lane];
      if (m > Bm || (m == Bm && i < Bi)) { Bm = m; Bi = i; }  // global first-index
      S2 += sm_s2[w][lane]; Cr += sm_cr[w][lane]; Q0 += sm_q0[w][lane];
    }

    float s_acc = 0.0f, n_acc = 0.0f;
    if (valid) {
      const float2 vv = ((const float2*)v)[jg];
      const bool vis = ((int)vv.x) == 1;

      float Sy2 = 0.0f, Sx2 = 0.0f;
#pragma unroll
      for (int p = 0; p < 14; ++p) {
        Sy2 = fmaf(uy[p], uy[p], Sy2);
        Sx2 = fmaf(ux[p], ux[p], Sx2);
      }
      const float maxy = 1.0f + gtap(2 * yi + 1) + gtap(27 - 2 * yi);
      const float maxx = 1.0f + gtap(2 * xi + 1) + gtap(27 - 2 * xi);
      const float inv = vis ? (1.0f / (maxy * maxx)) : 0.0f;

      // sum(h-tt)^2 = S2 - 2*inv*Cr + inv^2*Sy2*Sx2 ; row0 zeroed if invis
      float s = S2 - 2.0f * inv * Cr + inv * inv * Sy2 * Sx2;
      if (!vis) s -= Q0;

      // ---- coordinate loss (argmax-dependent gather) ----
      const int b = jg / NJ;
      const int j = jg - b * NJ;
      const int yC = Bi / 14;
      const int xC = Bi - 14 * yC;
      const size_t ob = ((size_t)b * (2 * NJ) + j) * TILE + (size_t)Bi;
      const float ox = o[ob];
      const float oy = o[ob + (size_t)NJ * TILE];
      const bool cond = Bm > 0.5f;
      const float sc = 1.0f / 14.0f;
      const float px = cond ? (ox + (float)xC) * sc : 0.0f;
      const float py = cond ? (oy + (float)yC) * sc : 0.0f;
      const float d0 = (px - tv.x) * vv.x;
      const float d1 = (py - tv.y) * vv.y;
      s += d0 * d0 + d1 * d1;

      s_acc = s;
      n_acc = vv.x + vv.y;
    }

    // ---- deterministic wave-0 reduction -> per-block partial ----
    s_acc = wave_sum(s_acc);
    n_acc = wave_sum(n_acc);
    if (lane == 0) {
      part[blockIdx.x]           = s_acc;
      part[nblocks + blockIdx.x] = n_acc;
      __threadfence();                       // release partials (device scope)
      const int tk = atomicAdd(ticket, 1);   // device-scope by default
      s_last = (tk == nblocks - 1);
    }
  }
  __syncthreads();

  // ---- last block (whichever it is) does the final reduction ----
  if (s_last) {
    __threadfence();   // acquire side
    float s = 0.0f, n = 0.0f;
    for (int i = threadIdx.x; i < nblocks; i += BLK) {
      s += __hip_atomic_load(&part[i],           __ATOMIC_RELAXED, __HIP_MEMORY_SCOPE_AGENT);
      n += __hip_atomic_load(&part[nblocks + i], __ATOMIC_RELAXED, __HIP_MEMORY_SCOPE_AGENT);
    }
    s = wave_sum(s);
    n = wave_sum(n);
    __shared__ float rs[4], rn[4];
    if (lane == 0) { rs[wid] = s; rn[wid] = n; }
    __syncthreads();
    if (threadIdx.x == 0) {
      const float S = rs[0] + rs[1] + rs[2] + rs[3];
      const float N = rn[0] + rn[1] + rn[2] + rn[3];
      out[0] = S / (0.5f * N);   // (d1_sum + d2_sum) / N1, N1 = sum(v)/2
    }
  }
}

extern "C" void kernel_launch(void* const* d_in, const int* in_sizes, int n_in,
                              void* d_out, int out_size, void* d_ws, size_t ws_size,
                              hipStream_t stream)
{
  const float* o = (const float*)d_in[0];  // [B, 2*NJ, 14, 14]
  const float* h = (const float*)d_in[1];  // [B, NJ, 14, 14]
  const float* t = (const float*)d_in[2];  // [B, NJ, 2]
  const float* v = (const float*)d_in[3];  // [B, NJ, 2]
  const int njoint = in_sizes[1] / TILE;          // B*NJ = 114688
  const int nblocks = (njoint + JPB - 1) / JPB;   // 1792 -> 7 blocks/CU exactly

  float* part  = (float*)d_ws;                 // 2*nblocks floats, rewritten each call
  int* ticket  = (int*)d_ws + 2 * nblocks;     // 4-byte ticket, zeroed each call

  hipMemsetAsync(ticket, 0, sizeof(int), stream);
  joint_kernel<<<nblocks, BLK, 0, stream>>>(o, h, t, v, part, ticket,
                                            (float*)d_out, njoint, nblocks);
}

// Round 5
// 29.907 us; speedup vs baseline: 3.2842x; 3.2842x over previous
//
#include <hip/hip_runtime.h>

// Problem constants: B=8192, NJ=14, COL=14, sigma=1, radius=4.
#define NJ    14
#define TILE  196          // 14*14 floats per tile
#define BLK   256
#define JPB   64           // joints per block (one per lane; 4 waves split the tile)
#define STAGE_DW (JPB * TILE)   // 12544 dwords = 50176 B staged per block

typedef __attribute__((address_space(1))) const void g_void;
typedef __attribute__((address_space(3))) void lds_void;

// exp(-0.5*d*d) with the 9-tap cutoff (|d|<=4), via v_exp_f32.
__device__ __forceinline__ float gtap(int d) {
  const int d2 = d * d;
  const float e = exp2f(-0.72134752044448169f * (float)d2);  // 0.5*log2(e)
  return (d2 <= 16) ? e : 0.0f;
}

// 1-D blurred-impulse response at position p for peak pk, with scipy
// 'reflect' padding folded in. Unnormalized (kernel-sum cancels in g/max).
__device__ __forceinline__ float uresp(int p, int pk) {
  float s = gtap(p - pk);
  if (p <= 3)  s += gtap(p + pk + 1);   // low reflection  (q<0 -> -1-q)
  if (p >= 10) s += gtap(27 - p - pk);  // high reflection (q>13 -> 27-q)
  return s;
}

__device__ __forceinline__ float wave_sum(float x) {
#pragma unroll
  for (int off = 32; off >= 1; off >>= 1) x += __shfl_xor(x, off);
  return x;
}

// Wave K processes float4 indices f = 4i + K of its lane's tile (from LDS).
// All tile indices are compile-time -> uy/ux stay in registers.
template<int K>
__device__ __forceinline__ void accum_part(const float4* __restrict__ hp,
    const float (&uy)[14], const float (&ux)[14],
    float& bm, int& bi, float& sh2, float& cross, float& q0)
{
  const int NI = (K == 0) ? 13 : 12;   // 49 float4 = 13+12+12+12
#pragma unroll
  for (int i = 0; i < NI; ++i) {
    const int f = 4 * i + K;
    const float4 q = hp[f];            // ds_read_b128, stride 784B
    const float qa[4] = {q.x, q.y, q.z, q.w};
#pragma unroll
    for (int c = 0; c < 4; ++c) {
      const int idx = 4 * f + c;
      const int y = idx / 14;
      const int x = idx - 14 * y;            // compile-time
      const float hv = qa[c];
      if (hv > bm) { bm = hv; bi = idx; }    // first-index within part
      sh2 = fmaf(hv, hv, sh2);
      if (y == 0) q0 = fmaf(hv, hv, q0);     // row-0 energy (invis fixup)
      cross = fmaf(hv, uy[y] * ux[x], cross);
    }
  }
}

__global__ __launch_bounds__(BLK, 3) void joint_kernel(
    const float* __restrict__ o, const float* __restrict__ h,
    const float* __restrict__ t, const float* __restrict__ v,
    float* __restrict__ part, int njoint, int nblocks)
{
  // 50176B stage buffer; reused (aliased) for the cross-wave reduction arrays.
  __shared__ __align__(16) float lds[STAGE_DW];

  const int tid  = threadIdx.x;
  const int lane = tid & 63;
  const int wid  = tid >> 6;
  const int jg   = blockIdx.x * JPB + lane;
  const bool valid = jg < njoint;

  // ---- coalesced global->LDS stage of this block's 64 tiles ----
  const int ntile = min(JPB, njoint - blockIdx.x * JPB);
  const int n4 = ntile * 49;                         // float4 count (3136)
  const float* gbase = h + (size_t)blockIdx.x * JPB * TILE;
#pragma unroll
  for (int i = 0; i < 13; ++i) {
    const int idx = i * BLK + tid;
    if (idx < n4) {
      __builtin_amdgcn_global_load_lds(
          (g_void*)(gbase + (size_t)idx * 4),        // per-lane global src
          (lds_void*)&lds[idx * 4],                  // wave-uniform base + lane*16
          16, 0, 0);
    }
  }

  // ---- overlap: per-joint analytic 1-D responses while loads fly ----
  float uy[14], ux[14];
  float2 tv = make_float2(0.0f, 0.0f);
  int xi = 0, yi = 0;
  if (valid) {
    tv = ((const float2*)t)[jg];
    xi = min(max((int)(tv.x * 14.0f), 0), 13);
    yi = min(max((int)(tv.y * 14.0f), 0), 13);
#pragma unroll
    for (int p = 0; p < 14; ++p) { uy[p] = uresp(p, yi); ux[p] = uresp(p, xi); }
  }

  asm volatile("s_waitcnt vmcnt(0)" ::: "memory");
  __syncthreads();

  // ---- per-wave partial pass over this lane's tile (from LDS) ----
  float bm = -3.0e38f; int bi = 0;
  float sh2 = 0.0f, cross = 0.0f, q0 = 0.0f;
  if (valid) {
    const float4* hp = (const float4*)&lds[lane * TILE];
    switch (wid) {   // wave-uniform branch: no lane divergence
      case 0: accum_part<0>(hp, uy, ux, bm, bi, sh2, cross, q0); break;
      case 1: accum_part<1>(hp, uy, ux, bm, bi, sh2, cross, q0); break;
      case 2: accum_part<2>(hp, uy, ux, bm, bi, sh2, cross, q0); break;
      default: accum_part<3>(hp, uy, ux, bm, bi, sh2, cross, q0); break;
    }
  }

  __syncthreads();   // all waves done READING tiles; safe to alias LDS
  float* red = lds;  // 5 arrays x 256 x 4B = 5120B, aliased into stage buffer
  red[0 * BLK + tid] = bm;
  ((int*)lds)[1 * BLK + tid] = bi;
  red[2 * BLK + tid] = sh2;
  red[3 * BLK + tid] = cross;
  red[4 * BLK + tid] = q0;
  __syncthreads();

  if (wid == 0) {
    // ---- combine the 4 parts for this lane's joint ----
    float Bm = red[lane]; int Bi = ((int*)lds)[BLK + lane];
    float S2 = red[2 * BLK + lane], Cr = red[3 * BLK + lane], Q0 = red[4 * BLK + lane];
#pragma unroll
    for (int w = 1; w < 4; ++w) {
      const float m = red[w * 64 + lane];
      const int   i = ((int*)lds)[BLK + w * 64 + lane];
      if (m > Bm || (m == Bm && i < Bi)) { Bm = m; Bi = i; }  // global first-index
      S2 += red[2 * BLK + w * 64 + lane];
      Cr += red[3 * BLK + w * 64 + lane];
      Q0 += red[4 * BLK + w * 64 + lane];
    }

    float s_acc = 0.0f, n_acc = 0.0f;
    if (valid) {
      const float2 vv = ((const float2*)v)[jg];
      const bool vis = ((int)vv.x) == 1;

      float Sy2 = 0.0f, Sx2 = 0.0f;
#pragma unroll
      for (int p = 0; p < 14; ++p) {
        Sy2 = fmaf(uy[p], uy[p], Sy2);
        Sx2 = fmaf(ux[p], ux[p], Sx2);
      }
      const float maxy = 1.0f + gtap(2 * yi + 1) + gtap(27 - 2 * yi);
      const float maxx = 1.0f + gtap(2 * xi + 1) + gtap(27 - 2 * xi);
      const float inv = vis ? (1.0f / (maxy * maxx)) : 0.0f;

      // sum(h-tt)^2 = S2 - 2*inv*Cr + inv^2*Sy2*Sx2 ; row0 zeroed if invis
      float s = S2 - 2.0f * inv * Cr + inv * inv * Sy2 * Sx2;
      if (!vis) s -= Q0;

      // ---- coordinate loss (argmax-dependent gather, stays global) ----
      const int b = jg / NJ;
      const int j = jg - b * NJ;
      const int yC = Bi / 14;
      const int xC = Bi - 14 * yC;
      const size_t ob = ((size_t)b * (2 * NJ) + j) * TILE + (size_t)Bi;
      const float ox = o[ob];
      const float oy = o[ob + (size_t)NJ * TILE];
      const bool cond = Bm > 0.5f;
      const float sc = 1.0f / 14.0f;
      const float px = cond ? (ox + (float)xC) * sc : 0.0f;
      const float py = cond ? (oy + (float)yC) * sc : 0.0f;
      const float d0 = (px - tv.x) * vv.x;
      const float d1 = (py - tv.y) * vv.y;
      s += d0 * d0 + d1 * d1;

      s_acc = s;
      n_acc = vv.x + vv.y;
    }

    // ---- deterministic wave-0 reduction -> per-block partial ----
    s_acc = wave_sum(s_acc);
    n_acc = wave_sum(n_acc);
    if (lane == 0) {
      part[blockIdx.x]           = s_acc;
      part[nblocks + blockIdx.x] = n_acc;
    }
  }
}

__global__ __launch_bounds__(BLK) void finalize_kernel(
    const float* __restrict__ part, float* __restrict__ out, int nblocks)
{
  float s = 0.0f, n = 0.0f;
  for (int i = threadIdx.x; i < nblocks; i += BLK) {
    s += part[i];
    n += part[nblocks + i];
  }
  s = wave_sum(s);
  n = wave_sum(n);
  __shared__ float rs[4], rn[4];
  const int lane = threadIdx.x & 63, wid = threadIdx.x >> 6;
  if (lane == 0) { rs[wid] = s; rn[wid] = n; }
  __syncthreads();
  if (threadIdx.x == 0) {
    const float S = rs[0] + rs[1] + rs[2] + rs[3];
    const float N = rn[0] + rn[1] + rn[2] + rn[3];
    out[0] = S / (0.5f * N);   // (d1_sum + d2_sum) / N1, N1 = sum(v)/2
  }
}

extern "C" void kernel_launch(void* const* d_in, const int* in_sizes, int n_in,
                              void* d_out, int out_size, void* d_ws, size_t ws_size,
                              hipStream_t stream)
{
  const float* o = (const float*)d_in[0];  // [B, 2*NJ, 14, 14]
  const float* h = (const float*)d_in[1];  // [B, NJ, 14, 14]
  const float* t = (const float*)d_in[2];  // [B, NJ, 2]
  const float* v = (const float*)d_in[3];  // [B, NJ, 2]
  const int njoint = in_sizes[1] / TILE;          // B*NJ = 114688
  const int nblocks = (njoint + JPB - 1) / JPB;   // 1792

  float* part = (float*)d_ws;  // 2*nblocks floats, fully rewritten each call
  joint_kernel<<<nblocks, BLK, 0, stream>>>(o, h, t, v, part, njoint, nblocks);
  finalize_kernel<<<1, BLK, 0, stream>>>(part, (float*)d_out, nblocks);
}